// Round 2
// baseline (206.514 us; speedup 1.0000x reference)
//
#include <hip/hip_runtime.h>

// DistanceCentroidLoss, round 9: occupancy-first restructure.
// Key realization: the MFMA 32x32x16 B-fragment is lane-contiguous in global
// memory (lane (l31,h) needs emb[row=l31][16s+8h..+8) = 8 consecutive floats),
// so the LDS transpose panel of r7/r8 is unnecessary. Dropping it frees
// ~64 VGPRs + 32KB LDS -> 4 blocks/CU (16 waves/CU) instead of 2 blocks/CU.
// GRID=2048, 1 tile/wave, TLP replaces the register ping-pong pipeline.
// A=centroids (64 rows, 2 accumulators, staged once per block in LDS),
// B=points (32 cols/wave, loaded directly into registers).
// d2 = x2 - 2*acc', acc' = dot - c2/2 (C initialized to -c2/2 via LDS tables).
// C/D layout (32x32x16): col = lane&31 (point), row = (reg&3) + 8*(reg>>2) + 4*(lane>>5).

constexpr int N = 262144;
constexpr int D = 128;
constexpr int K = 64;

constexpr int GRID = 2048;            // 4 waves/block, 1 tile/wave -> 8192 tiles, zero tail

typedef __bf16 bf16x8 __attribute__((ext_vector_type(8)));
typedef float  f32x16 __attribute__((ext_vector_type(16)));

__global__ __launch_bounds__(256, 4) void dcl_main(
    const float* __restrict__ emb,
    const int*   __restrict__ labels,
    const float* __restrict__ cent,
    float* __restrict__ g_attr,
    float* __restrict__ g_rep,
    int*   __restrict__ g_cnt)
{
    __shared__ bf16x8 sA[2 * 8 * 64];                    // 16 KB A-fragments
    __shared__ float  s_c2[K];
    __shared__ __align__(16) float sC2i0[2][16];         // -c2/2 acc0 init, [h][r]
    __shared__ __align__(16) float sC2i1[2][16];         // -c2/2 acc1 init, [h][r]
    __shared__ float  s_attr[K];
    __shared__ float  s_rep[K];
    __shared__ int    s_cnt[K];

    const int tid  = threadIdx.x;
    const int wave = tid >> 6;
    const int lane = tid & 63;
    const int l31  = lane & 31;
    const int h    = lane >> 5;

    const int tile = blockIdx.x * 4 + wave;
    const int row  = tile * 32 + l31;

    // --- issue all 16 B-fragment loads immediately (lane-direct, no transpose) ---
    // lane (l31,h) step s covers dims [16s+8h, 16s+8h+8) = float4 idx {4s+2h, 4s+2h+1}
    const float4* row4 = (const float4*)emb + (size_t)row * 32 + 2 * h;
    float4 f[16];
    #pragma unroll
    for (int s = 0; s < 8; ++s) {
        f[2 * s]     = row4[4 * s];
        f[2 * s + 1] = row4[4 * s + 1];
    }
    const int li = labels[row];

    // --- stage centroid A-fragments into LDS while point loads fly ---
    #pragma unroll
    for (int e = tid; e < 2 * 8 * 64; e += 256) {
        const int t = e >> 9, s = (e >> 6) & 7, l = e & 63;
        const int c  = t * 32 + (l & 31);
        const int d0 = 16 * s + 8 * (l >> 5);
        const float4 f0 = *(const float4*)(cent + c * D + d0);
        const float4 f1 = *(const float4*)(cent + c * D + d0 + 4);
        bf16x8 v;
        v[0] = (__bf16)f0.x; v[1] = (__bf16)f0.y; v[2] = (__bf16)f0.z; v[3] = (__bf16)f0.w;
        v[4] = (__bf16)f1.x; v[5] = (__bf16)f1.y; v[6] = (__bf16)f1.z; v[7] = (__bf16)f1.w;
        sA[e] = v;
    }
    if (tid < K) {
        const float4* cp = (const float4*)(cent + tid * D);
        float sa = 0.f, sb = 0.f;
        #pragma unroll
        for (int q = 0; q < D / 8; ++q) {
            const float4 fq = cp[2 * q];
            const float4 gg = cp[2 * q + 1];
            sa = fmaf(fq.x, fq.x, sa); sa = fmaf(fq.y, fq.y, sa);
            sa = fmaf(fq.z, fq.z, sa); sa = fmaf(fq.w, fq.w, sa);
            sb = fmaf(gg.x, gg.x, sb); sb = fmaf(gg.y, gg.y, sb);
            sb = fmaf(gg.z, gg.z, sb); sb = fmaf(gg.w, gg.w, sb);
        }
        s_c2[tid] = sa + sb;
        s_attr[tid] = 0.f; s_rep[tid] = 0.f; s_cnt[tid] = 0;
    }
    __syncthreads();
    if (tid < 32) {
        const int hh = tid >> 4, r = tid & 15;
        const int rb = (r & 3) + 8 * (r >> 2) + 4 * hh;
        sC2i0[hh][r] = -0.5f * s_c2[rb];
        sC2i1[hh][r] = -0.5f * s_c2[rb + 32];
    }
    __syncthreads();

    // --- convert to bf16 fragments + x2 (same op order as r8: numerically identical) ---
    bf16x8 b[8];
    float x2A = 0.f, x2B = 0.f;
    #pragma unroll
    for (int s = 0; s < 8; ++s) {
        const float4 f0 = f[2 * s], f1 = f[2 * s + 1];
        bf16x8 v;
        v[0] = (__bf16)f0.x; v[1] = (__bf16)f0.y; v[2] = (__bf16)f0.z; v[3] = (__bf16)f0.w;
        v[4] = (__bf16)f1.x; v[5] = (__bf16)f1.y; v[6] = (__bf16)f1.z; v[7] = (__bf16)f1.w;
        b[s] = v;
        const float e0 = (float)v[0], e1 = (float)v[1], e2 = (float)v[2], e3 = (float)v[3];
        const float e4 = (float)v[4], e5 = (float)v[5], e6 = (float)v[6], e7 = (float)v[7];
        float p0 = e0 * e0; p0 = fmaf(e1, e1, p0); p0 = fmaf(e2, e2, p0); p0 = fmaf(e3, e3, p0);
        float p1 = e4 * e4; p1 = fmaf(e5, e5, p1); p1 = fmaf(e6, e6, p1); p1 = fmaf(e7, e7, p1);
        x2A += p0; x2B += p1;
    }

    f32x16 acc0, acc1;
    {
        const float4* p0 = (const float4*)&sC2i0[h][0];
        const float4* p1 = (const float4*)&sC2i1[h][0];
        #pragma unroll
        for (int w = 0; w < 4; ++w) {
            ((float4*)&acc0)[w] = p0[w];
            ((float4*)&acc1)[w] = p1[w];
        }
    }

    __builtin_amdgcn_s_setprio(1);
    #pragma unroll
    for (int s = 0; s < 8; ++s) {
        const bf16x8 a0 = sA[s * 64 + lane];
        const bf16x8 a1 = sA[(8 + s) * 64 + lane];
        acc0 = __builtin_amdgcn_mfma_f32_32x32x16_bf16(a0, b[s], acc0, 0, 0, 0);
        acc1 = __builtin_amdgcn_mfma_f32_32x32x16_bf16(a1, b[s], acc1, 0, 0, 0);
    }
    __builtin_amdgcn_s_setprio(0);

    const float x2p = x2A + x2B;
    const float x2 = x2p + __shfl_xor(x2p, 32);

    float s1a = 0.f, s1b = 0.f, s2a = 0.f, s2b = 0.f, own = 0.f;
    #pragma unroll
    for (int r = 0; r < 16; ++r) {
        const int rbase = (r & 3) + 8 * (r >> 2) + 4 * h;
        {
            float d2 = fmaf(-2.f, acc0[r], x2);
            d2 = fmaxf(d2, 0.f);
            const float dd = __builtin_amdgcn_sqrtf(d2);
            s1a += dd; s2a += d2;
            if (rbase == li) own += d2;
        }
        {
            float d2 = fmaf(-2.f, acc1[r], x2);
            d2 = fmaxf(d2, 0.f);
            const float dd = __builtin_amdgcn_sqrtf(d2);
            s1b += dd; s2b += d2;
            if (rbase + 32 == li) own += d2;
        }
    }
    float s1 = s1a + s1b, s2 = s2a + s2b;
    s1  += __shfl_xor(s1, 32);
    s2  += __shfl_xor(s2, 32);
    own += __shfl_xor(own, 32);

    if (lane < 32) {
        const float down = __builtin_amdgcn_sqrtf(own);
        const float own_term = fmaf(-10.f, down, 25.f) + own;   // (5 - d_own)^2
        const float row_other = (25.f * K - 10.f * s1 + s2 - own_term) * (1.f / (K - 1));
        atomicAdd(&s_attr[li], own);
        atomicAdd(&s_rep[li], row_other);
        atomicAdd(&s_cnt[li], 1);
    }

    __syncthreads();
    if (tid < K) {
        const int rep8 = (blockIdx.x & 7) * K;   // spread contention 8-way
        atomicAdd(&g_attr[rep8 + tid], s_attr[tid]);
        atomicAdd(&g_rep[rep8 + tid], s_rep[tid]);
        atomicAdd(&g_cnt[rep8 + tid], s_cnt[tid]);
    }
}

__global__ void dcl_finish(const float* __restrict__ g_attr,
                           const float* __restrict__ g_rep,
                           const int*   __restrict__ g_cnt,
                           float* __restrict__ out)
{
    const int k = threadIdx.x;  // 64 threads = 1 wave
    float a = 0.f, r = 0.f;
    int   c = 0;
    #pragma unroll
    for (int j = 0; j < 8; ++j) {
        a += g_attr[j * K + k];
        r += g_rep[j * K + k];
        c += g_cnt[j * K + k];
    }
    float v = (c > 0) ? (a + r) / (float)c : 0.f;
    #pragma unroll
    for (int off = 32; off > 0; off >>= 1) v += __shfl_down(v, off);
    if (k == 0) out[0] = v * (1.f / K);
}

extern "C" void kernel_launch(void* const* d_in, const int* in_sizes, int n_in,
                              void* d_out, int out_size, void* d_ws, size_t ws_size,
                              hipStream_t stream) {
    const float* emb    = (const float*)d_in[0];
    const int*   labels = (const int*)d_in[1];
    const float* cent   = (const float*)d_in[2];
    float* out = (float*)d_out;

    float* g_attr = (float*)d_ws;                 // [8][64]
    float* g_rep  = g_attr + 8 * K;               // [8][64]
    int*   g_cnt  = (int*)(g_rep + 8 * K);        // [8][64]

    hipMemsetAsync(d_ws, 0, 3 * 8 * K * sizeof(float), stream);
    dcl_main<<<GRID, 256, 0, stream>>>(emb, labels, cent, g_attr, g_rep, g_cnt);
    dcl_finish<<<1, 64, 0, stream>>>(g_attr, g_rep, g_cnt, out);
}